// Round 4
// baseline (238.149 us; speedup 1.0000x reference)
//
#include <hip/hip_runtime.h>

typedef _Float16 f16x8  __attribute__((ext_vector_type(8)));
typedef __fp16   h16x2  __attribute__((ext_vector_type(2)));
typedef float    f32x4  __attribute__((ext_vector_type(4)));
typedef float    f32x16 __attribute__((ext_vector_type(16)));

#define NLAYER 5
#define NTILES 8192          // 1048576 / 128 rows per block-pass
#define GRID   2048          // each block loops 4 tiles

static __device__ __forceinline__ int pkrtz(float a, float b) {
    h16x2 p = __builtin_amdgcn_cvt_pkrtz(a, b);
    return __builtin_bit_cast(int, p);
}

// v_permlane32_swap_b32 DST, SRC  (CDNA4):
//   new_DST = {DST[0:31],  SRC[0:31]}   (DST.hi <- SRC.lo)
//   new_SRC = {DST[32:63], SRC[32:63]}  (SRC.lo <- DST.hi)
// One op yields both the "low-halves" dword and the "high-halves" dword.
static __device__ __forceinline__ void plswap(int& a, int& b) {
    asm("v_permlane32_swap_b32 %0, %1" : "+v"(a), "+v"(b));
}

// ---------------------------------------------------------------------------
// Prep: convert f32 weights -> fp16 in exact MFMA A-fragment order:
//   half index = ((((L*2+t)*4+f)*64)+lane)*8 + e
//   value      = W[L][w = 32t + (lane&31)][k = 8*(lane>>5) + 16f + e]
// ---------------------------------------------------------------------------
__global__ __launch_bounds__(256) void prep_weights(
    const float* __restrict__ w_in, const float* __restrict__ w_hid,
    const float* __restrict__ w_out, _Float16* __restrict__ wf)
{
    int idx = blockIdx.x * 256 + threadIdx.x;      // exactly 20480 threads
    int e = idx & 7;
    int l = (idx >> 3) & 63;
    int f = (idx >> 9) & 3;
    int t = (idx >> 11) & 1;
    int L = idx >> 12;
    int w = t * 32 + (l & 31);
    int k = ((l >> 5) << 3) + (f << 4) + e;
    float v;
    if (L == 0)       v = w_in[w * 64 + k];
    else if (L <= 3)  v = w_hid[((L - 1) * 64 + w) * 64 + k];
    else              v = w_out[w * 64 + k];
    wf[idx] = (_Float16)v;
}

// ---------------------------------------------------------------------------
// Fused MLP. Per wave: 32 batch rows, all 5 layers in registers.
//  - B-frag (activations): col b = lane&31 (layer-invariant), k = 8*(lane>>5)+e
//  - A-frag (weights, LDS): row w = lane&31, k = 8*(lane>>5)+e
//  - C/D layout: col = lane&31, row = (reg&3) + 8*(reg>>2) + 4*(lane>>5)
//  Inter-layer: relu -> cvt_pkrtz -> half-wave exchange via permlane32_swap.
//  Next tile's x is register-prefetched under the 5-layer chain.
// ---------------------------------------------------------------------------
__global__ __launch_bounds__(256) void mlp_kernel(
    const float* __restrict__ x, const f16x8* __restrict__ wfrag_g,
    float* __restrict__ out)
{
    __shared__ f16x8 Wlds[NLAYER * 8 * 64];        // 40960 B

    const int tid = threadIdx.x;
    {   // linear 40 KB fill, coalesced float4, frag order already correct
        const float4* src = (const float4*)wfrag_g;
        float4*       dst = (float4*)Wlds;
#pragma unroll
        for (int i = 0; i < 10; ++i) dst[tid + i * 256] = src[tid + i * 256];
    }
    __syncthreads();

    const int lane = tid & 63;
    const int wid  = tid >> 6;
    const int g    = lane >> 5;      // 0/1 : k-half
    const int bl   = lane & 31;      // batch column within tile

    float4 xa[4], xb[4];
    {   // first tile's loads (only exposed latency in the whole loop)
        const int row = blockIdx.x * 128 + wid * 32 + bl;
        const float4* xp = (const float4*)(x + (size_t)row * 64) + 2 * g;
#pragma unroll
        for (int F = 0; F < 4; ++F) { xa[F] = xp[4 * F]; xb[F] = xp[4 * F + 1]; }
    }

    for (int T = blockIdx.x; T < NTILES; T += GRID) {
        const int row = T * 128 + wid * 32 + bl;

        // ---- consume prefetched x -> layer-0 B-fragments -------------------
        f16x8 h[4];
#pragma unroll
        for (int F = 0; F < 4; ++F) {
            int4 packed = make_int4(pkrtz(xa[F].x, xa[F].y),
                                    pkrtz(xa[F].z, xa[F].w),
                                    pkrtz(xb[F].x, xb[F].y),
                                    pkrtz(xb[F].z, xb[F].w));
            h[F] = __builtin_bit_cast(f16x8, packed);
        }

        // ---- prefetch next tile's x under the 5-layer chain ----------------
        const int Tn = T + GRID;
        if (Tn < NTILES) {
            const int nrow = Tn * 128 + wid * 32 + bl;
            const float4* xp = (const float4*)(x + (size_t)nrow * 64) + 2 * g;
#pragma unroll
            for (int F = 0; F < 4; ++F) { xa[F] = xp[4 * F]; xb[F] = xp[4 * F + 1]; }
        }

        // ---- 5 layers ------------------------------------------------------
#pragma unroll
        for (int L = 0; L < NLAYER; ++L) {
            f32x16 acc0, acc1;
#pragma unroll
            for (int i = 0; i < 16; ++i) { acc0[i] = 0.0f; acc1[i] = 0.0f; }

            const f16x8* WL = &Wlds[L * 8 * 64];
#pragma unroll
            for (int f = 0; f < 4; ++f) {
                acc0 = __builtin_amdgcn_mfma_f32_32x32x16_f16(
                           WL[f * 64 + lane],       h[f], acc0, 0, 0, 0);
                acc1 = __builtin_amdgcn_mfma_f32_32x32x16_f16(
                           WL[(4 + f) * 64 + lane], h[f], acc1, 0, 0, 0);
            }

            if (L < NLAYER - 1) {
                // relu + pack: c[t][j] covers w = 32t + 4g + 8*(j>>1) + 2*(j&1)+{0,1}
                int c[2][8];
#pragma unroll
                for (int j = 0; j < 8; ++j) {
                    c[0][j] = pkrtz(fmaxf(acc0[2 * j], 0.0f),
                                    fmaxf(acc0[2 * j + 1], 0.0f));
                    c[1][j] = pkrtz(fmaxf(acc1[2 * j], 0.0f),
                                    fmaxf(acc1[2 * j + 1], 0.0f));
                }
                // rebuild next-layer B-fragments: frag F dword d holds
                //   k = 16F + 8g + 2d .. +1   (half-wave exchange, 1 op/2 dwords)
#pragma unroll
                for (int F = 0; F < 4; ++F) {
                    const int t = F >> 1;
                    int dw[4];
#pragma unroll
                    for (int p = 0; p < 2; ++p) {
                        int xv = c[t][((2 * F) & 3) * 2 + p];
                        int yv = c[t][((2 * F + 1) & 3) * 2 + p];
                        plswap(xv, yv);          // xv={x_lo,y_lo} yv={x_hi,y_hi}
                        dw[p]     = xv;
                        dw[p + 2] = yv;
                    }
                    int4 packed = make_int4(dw[0], dw[1], dw[2], dw[3]);
                    h[F] = __builtin_bit_cast(f16x8, packed);
                }
            } else {
                // ---- store f32 output (nontemporal: streamed, never re-read)
                float* orow = out + (size_t)row * 64 + g * 4;
#pragma unroll
                for (int q = 0; q < 4; ++q) {
                    f32x4 v0 = { acc0[4 * q], acc0[4 * q + 1],
                                 acc0[4 * q + 2], acc0[4 * q + 3] };
                    __builtin_nontemporal_store(v0, (f32x4*)(orow + q * 8));
                    f32x4 v1 = { acc1[4 * q], acc1[4 * q + 1],
                                 acc1[4 * q + 2], acc1[4 * q + 3] };
                    __builtin_nontemporal_store(v1, (f32x4*)(orow + 32 + q * 8));
                }
            }
        }
    }
}

extern "C" void kernel_launch(void* const* d_in, const int* in_sizes, int n_in,
                              void* d_out, int out_size, void* d_ws, size_t ws_size,
                              hipStream_t stream)
{
    const float* x    = (const float*)d_in[0];
    const float* w_in = (const float*)d_in[1];
    const float* w_h  = (const float*)d_in[2];
    const float* w_o  = (const float*)d_in[3];

    _Float16* wf = (_Float16*)d_ws;                 // 20480 halves = 40 KB
    prep_weights<<<80, 256, 0, stream>>>(w_in, w_h, w_o, wf);
    mlp_kernel<<<GRID, 256, 0, stream>>>(x, (const f16x8*)d_ws, (float*)d_out);
}

// Round 5
// 143.441 us; speedup vs baseline: 1.6603x; 1.6603x over previous
//
#include <hip/hip_runtime.h>

typedef _Float16 f16x8  __attribute__((ext_vector_type(8)));
typedef __fp16   h16x2  __attribute__((ext_vector_type(2)));
typedef float    f32x16 __attribute__((ext_vector_type(16)));

#define NLAYER 5
#define BLOCK  512
#define WAVES  8
#define ROWS   256           // rows per block-tile (32 per wave)
#define NTILES 4096          // 1048576 / 256
#define GRID   1024          // 4 tiles per block

static __device__ __forceinline__ int pkrtz(float a, float b) {
    h16x2 p = __builtin_amdgcn_cvt_pkrtz(a, b);
    return __builtin_bit_cast(int, p);
}

// v_permlane32_swap_b32: one op swaps lane[i]<->lane[i+32] halves of two regs.
static __device__ __forceinline__ void plswap(int& a, int& b) {
    asm("v_permlane32_swap_b32 %0, %1" : "+v"(a), "+v"(b));
}

// ---------------------------------------------------------------------------
// Prep: f32 weights -> fp16 in exact MFMA A-fragment order:
//   half index = ((((L*2+t)*4+f)*64)+lane)*8 + e
//   value      = W[L][w = 32t + (lane&31)][k = 8*(lane>>5) + 16f + e]
// ---------------------------------------------------------------------------
__global__ __launch_bounds__(256) void prep_weights(
    const float* __restrict__ w_in, const float* __restrict__ w_hid,
    const float* __restrict__ w_out, _Float16* __restrict__ wf)
{
    int idx = blockIdx.x * 256 + threadIdx.x;      // exactly 20480 threads
    int e = idx & 7;
    int l = (idx >> 3) & 63;
    int f = (idx >> 9) & 3;
    int t = (idx >> 11) & 1;
    int L = idx >> 12;
    int w = t * 32 + (l & 31);
    int k = ((l >> 5) << 3) + (f << 4) + e;
    float v;
    if (L == 0)       v = w_in[w * 64 + k];
    else if (L <= 3)  v = w_hid[((L - 1) * 64 + w) * 64 + k];
    else              v = w_out[w * 64 + k];
    wf[idx] = (_Float16)v;
}

// ---------------------------------------------------------------------------
// Fused MLP, coalesced-load version.
//  Per wave: 32 batch rows = contiguous 8KB of x. Coalesced lane-contiguous
//  dwordx4 loads -> fp16 in reg -> per-wave LDS tile (XOR-swizzled) ->
//  ds_read_b128 MFMA B-fragments. No inter-wave syncs in the main loop.
//  - B-frag: col b = lane&31 (layer-invariant), k = 8*(lane>>5)+e
//  - A-frag (weights, LDS): row w = lane&31, k = 8*(lane>>5)+e
//  - C/D: col = lane&31, row = (reg&3) + 8*(reg>>2) + 4*(lane>>5)
//  Inter-layer: relu -> cvt_pkrtz -> permlane32_swap half-wave exchange.
//  Next tile's x register-prefetched under the 5-layer chain.
// ---------------------------------------------------------------------------
__global__ __launch_bounds__(BLOCK, 4) void mlp_kernel(
    const float* __restrict__ x, const f16x8* __restrict__ wfrag_g,
    float* __restrict__ out)
{
    __shared__ f16x8 Wlds[NLAYER * 8 * 64];                    // 40960 B
    __shared__ __align__(16) _Float16 xlds[WAVES][32 * 64];    // 32768 B

    const int tid = threadIdx.x;
    {   // weights: linear 40 KB fill, coalesced float4, frag order pre-baked
        const float4* src = (const float4*)wfrag_g;
        float4*       dst = (float4*)Wlds;
#pragma unroll
        for (int i = 0; i < 5; ++i) dst[tid + i * BLOCK] = src[tid + i * BLOCK];
    }
    __syncthreads();

    const int lane = tid & 63;
    const int wid  = tid >> 6;
    const int g    = lane >> 5;      // 0/1 : k-half
    const int bl   = lane & 31;      // batch column within wave-tile

    char* xw = (char*)&xlds[wid][0];

    // LDS addresses (bytes). Swizzle: byte ^= ((row&7)<<4) within each row.
    int wr[8];
    {
        const int c8 = (lane & 15) * 8;            // col-byte (fp16), 8B piece
#pragma unroll
        for (int j = 0; j < 8; ++j) {
            const int r = j * 4 + (lane >> 4);     // row 0..31
            wr[j] = r * 128 + (c8 ^ ((r & 7) << 4));
        }
    }
    int rd[4];
#pragma unroll
    for (int F = 0; F < 4; ++F)
        rd[F] = bl * 128 + ((F * 32 + g * 16) ^ ((bl & 7) << 4));

    // prologue: coalesced load of first tile's 8KB (1KB per instruction)
    float4 px[8];
    {
        const float4* xb = (const float4*)(x + (size_t)(blockIdx.x * ROWS + wid * 32) * 64);
#pragma unroll
        for (int j = 0; j < 8; ++j) px[j] = xb[j * 64 + lane];
    }

    for (int T = blockIdx.x; T < NTILES; T += GRID) {
        // ---- convert + stage into own LDS region (swizzled) ----------------
#pragma unroll
        for (int j = 0; j < 8; ++j) {
            int2 v = make_int2(pkrtz(px[j].x, px[j].y), pkrtz(px[j].z, px[j].w));
            *(int2*)(xw + wr[j]) = v;
        }
        // ---- fragment reads (intra-wave ordering via lgkmcnt) --------------
        f16x8 h[4];
#pragma unroll
        for (int F = 0; F < 4; ++F) h[F] = *(const f16x8*)(xw + rd[F]);

        // ---- prefetch next tile's x (coalesced) under the layer chain ------
        const int Tn = T + GRID;
        if (Tn < NTILES) {
            const float4* xb = (const float4*)(x + (size_t)(Tn * ROWS + wid * 32) * 64);
#pragma unroll
            for (int j = 0; j < 8; ++j) px[j] = xb[j * 64 + lane];
        }

        const int row = T * ROWS + wid * 32 + bl;

        // ---- 5 layers ------------------------------------------------------
#pragma unroll
        for (int L = 0; L < NLAYER; ++L) {
            f32x16 acc0, acc1;
#pragma unroll
            for (int i = 0; i < 16; ++i) { acc0[i] = 0.0f; acc1[i] = 0.0f; }

            const f16x8* WL = &Wlds[L * 8 * 64];
#pragma unroll
            for (int f = 0; f < 4; ++f) {
                acc0 = __builtin_amdgcn_mfma_f32_32x32x16_f16(
                           WL[f * 64 + lane],       h[f], acc0, 0, 0, 0);
                acc1 = __builtin_amdgcn_mfma_f32_32x32x16_f16(
                           WL[(4 + f) * 64 + lane], h[f], acc1, 0, 0, 0);
            }

            if (L < NLAYER - 1) {
                // relu + pack: c[t][j] covers w = 32t + 4g + 8*(j>>1) + 2*(j&1)+{0,1}
                int c[2][8];
#pragma unroll
                for (int j = 0; j < 8; ++j) {
                    c[0][j] = pkrtz(fmaxf(acc0[2 * j], 0.0f),
                                    fmaxf(acc0[2 * j + 1], 0.0f));
                    c[1][j] = pkrtz(fmaxf(acc1[2 * j], 0.0f),
                                    fmaxf(acc1[2 * j + 1], 0.0f));
                }
                // next-layer B-fragments: frag F dword d holds k = 16F+8g+2d..+1
#pragma unroll
                for (int F = 0; F < 4; ++F) {
                    const int t = F >> 1;
                    int dw[4];
#pragma unroll
                    for (int p = 0; p < 2; ++p) {
                        int xv = c[t][((2 * F) & 3) * 2 + p];
                        int yv = c[t][((2 * F + 1) & 3) * 2 + p];
                        plswap(xv, yv);          // xv={x_lo,y_lo} yv={x_hi,y_hi}
                        dw[p]     = xv;
                        dw[p + 2] = yv;
                    }
                    int4 packed = make_int4(dw[0], dw[1], dw[2], dw[3]);
                    h[F] = __builtin_bit_cast(f16x8, packed);
                }
            } else {
                // ---- plain f32 stores (L2 merges the strided 16B pieces) ---
                float* orow = out + (size_t)row * 64 + g * 4;
#pragma unroll
                for (int q = 0; q < 4; ++q) {
                    float4 v0 = make_float4(acc0[4 * q], acc0[4 * q + 1],
                                            acc0[4 * q + 2], acc0[4 * q + 3]);
                    *(float4*)(orow + q * 8) = v0;
                    float4 v1 = make_float4(acc1[4 * q], acc1[4 * q + 1],
                                            acc1[4 * q + 2], acc1[4 * q + 3]);
                    *(float4*)(orow + 32 + q * 8) = v1;
                }
            }
        }
    }
}

extern "C" void kernel_launch(void* const* d_in, const int* in_sizes, int n_in,
                              void* d_out, int out_size, void* d_ws, size_t ws_size,
                              hipStream_t stream)
{
    const float* x    = (const float*)d_in[0];
    const float* w_in = (const float*)d_in[1];
    const float* w_h  = (const float*)d_in[2];
    const float* w_o  = (const float*)d_in[3];

    _Float16* wf = (_Float16*)d_ws;                 // 20480 halves = 40 KB
    prep_weights<<<80, 256, 0, stream>>>(w_in, w_h, w_o, wf);
    mlp_kernel<<<GRID, BLOCK, 0, stream>>>(x, (const f16x8*)d_ws, (float*)d_out);
}

// Round 6
// 120.015 us; speedup vs baseline: 1.9843x; 1.1952x over previous
//
#include <hip/hip_runtime.h>

typedef _Float16 f16x8  __attribute__((ext_vector_type(8)));
typedef __fp16   h16x2  __attribute__((ext_vector_type(2)));
typedef float    f32x16 __attribute__((ext_vector_type(16)));

#define NLAYER 5
#define BLOCK  512
#define WAVES  8
#define ROWS   256           // rows per block-tile (32 per wave)
#define NTILES 4096          // 1048576 / 256
#define GRID   1024          // 4 tiles per block

static __device__ __forceinline__ int pkrtz(float a, float b) {
    h16x2 p = __builtin_amdgcn_cvt_pkrtz(a, b);
    return __builtin_bit_cast(int, p);
}

// v_permlane32_swap_b32: one op swaps lane[i]<->lane[i+32] halves of two regs.
static __device__ __forceinline__ void plswap(int& a, int& b) {
    asm("v_permlane32_swap_b32 %0, %1" : "+v"(a), "+v"(b));
}

// ---------------------------------------------------------------------------
// Prep: f32 weights -> fp16 in exact MFMA fragment order:
//   half index = ((((L*2+t)*4+f)*64)+lane)*8 + e
//   value      = W[L][w = 32t + (lane&31)][k = 8*(lane>>5) + 16f + e]
// Same per-lane mapping serves as A-frag (hidden layers) and B-frag (final).
// ---------------------------------------------------------------------------
__global__ __launch_bounds__(256) void prep_weights(
    const float* __restrict__ w_in, const float* __restrict__ w_hid,
    const float* __restrict__ w_out, _Float16* __restrict__ wf)
{
    int idx = blockIdx.x * 256 + threadIdx.x;      // exactly 20480 threads
    int e = idx & 7;
    int l = (idx >> 3) & 63;
    int f = (idx >> 9) & 3;
    int t = (idx >> 11) & 1;
    int L = idx >> 12;
    int w = t * 32 + (l & 31);
    int k = ((l >> 5) << 3) + (f << 4) + e;
    float v;
    if (L == 0)       v = w_in[w * 64 + k];
    else if (L <= 3)  v = w_hid[((L - 1) * 64 + w) * 64 + k];
    else              v = w_out[w * 64 + k];
    wf[idx] = (_Float16)v;
}

// ---------------------------------------------------------------------------
// Fused MLP, coalesced loads AND stores.
//  Hidden layers (L=0..3): mfma(A=W, B=h) -> col = batch (layer-invariant);
//    relu -> cvt_pkrtz -> permlane32_swap half-wave exchange.
//  Final layer: SWAPPED operands mfma(A=h, B=W) -> col = feature, batch in
//    the reg pattern -> 32 dword stores, each two full 128B line-aligned
//    chunks (fully coalesced; fixes the 1.8 TB/s scattered-store cap).
//  x path: coalesced dwordx4 -> fp16 -> per-wave swizzled LDS -> b128 frags.
//  Next tile's x register-prefetched under the 5-layer chain.
// ---------------------------------------------------------------------------
__global__ __launch_bounds__(BLOCK, 4) void mlp_kernel(
    const float* __restrict__ x, const f16x8* __restrict__ wfrag_g,
    float* __restrict__ out)
{
    __shared__ f16x8 Wlds[NLAYER * 8 * 64];                    // 40960 B
    __shared__ __align__(16) _Float16 xlds[WAVES][32 * 64];    // 32768 B

    const int tid = threadIdx.x;
    {   // weights: linear 40 KB fill, coalesced float4, frag order pre-baked
        const float4* src = (const float4*)wfrag_g;
        float4*       dst = (float4*)Wlds;
#pragma unroll
        for (int i = 0; i < 5; ++i) dst[tid + i * BLOCK] = src[tid + i * BLOCK];
    }
    __syncthreads();

    const int lane = tid & 63;
    const int wid  = tid >> 6;
    const int g    = lane >> 5;      // 0/1 : k-half
    const int bl   = lane & 31;      // batch column within wave-tile

    char* xw = (char*)&xlds[wid][0];

    // LDS addresses (bytes). Swizzle: byte ^= ((row&7)<<4) within each row.
    int wr[8];
    {
        const int c8 = (lane & 15) * 8;            // col-byte (fp16), 8B piece
#pragma unroll
        for (int j = 0; j < 8; ++j) {
            const int r = j * 4 + (lane >> 4);     // row 0..31
            wr[j] = r * 128 + (c8 ^ ((r & 7) << 4));
        }
    }
    int rd[4];
#pragma unroll
    for (int F = 0; F < 4; ++F)
        rd[F] = bl * 128 + ((F * 32 + g * 16) ^ ((bl & 7) << 4));

    // prologue: coalesced load of first tile's 8KB (1KB per instruction)
    float4 px[8];
    {
        const float4* xb = (const float4*)(x + (size_t)(blockIdx.x * ROWS + wid * 32) * 64);
#pragma unroll
        for (int j = 0; j < 8; ++j) px[j] = xb[j * 64 + lane];
    }

    for (int T = blockIdx.x; T < NTILES; T += GRID) {
        // ---- convert + stage into own LDS region (swizzled) ----------------
#pragma unroll
        for (int j = 0; j < 8; ++j) {
            int2 v = make_int2(pkrtz(px[j].x, px[j].y), pkrtz(px[j].z, px[j].w));
            *(int2*)(xw + wr[j]) = v;
        }
        // ---- fragment reads (intra-wave ordering via lgkmcnt) --------------
        f16x8 h[4];
#pragma unroll
        for (int F = 0; F < 4; ++F) h[F] = *(const f16x8*)(xw + rd[F]);

        // ---- prefetch next tile's x (coalesced) under the layer chain ------
        const int Tn = T + GRID;
        if (Tn < NTILES) {
            const float4* xb = (const float4*)(x + (size_t)(Tn * ROWS + wid * 32) * 64);
#pragma unroll
            for (int j = 0; j < 8; ++j) px[j] = xb[j * 64 + lane];
        }

        const int base = T * ROWS + wid * 32;

        // ---- 4 hidden layers: A=W, B=h (col = batch) -----------------------
#pragma unroll
        for (int L = 0; L < NLAYER - 1; ++L) {
            f32x16 acc0, acc1;
#pragma unroll
            for (int i = 0; i < 16; ++i) { acc0[i] = 0.0f; acc1[i] = 0.0f; }

            const f16x8* WL = &Wlds[L * 8 * 64];
#pragma unroll
            for (int f = 0; f < 4; ++f) {
                acc0 = __builtin_amdgcn_mfma_f32_32x32x16_f16(
                           WL[f * 64 + lane],       h[f], acc0, 0, 0, 0);
                acc1 = __builtin_amdgcn_mfma_f32_32x32x16_f16(
                           WL[(4 + f) * 64 + lane], h[f], acc1, 0, 0, 0);
            }

            // relu + pack: c[t][j] covers w = 32t + 4g + 8*(j>>1) + 2*(j&1)+{0,1}
            int c[2][8];
#pragma unroll
            for (int j = 0; j < 8; ++j) {
                c[0][j] = pkrtz(fmaxf(acc0[2 * j], 0.0f),
                                fmaxf(acc0[2 * j + 1], 0.0f));
                c[1][j] = pkrtz(fmaxf(acc1[2 * j], 0.0f),
                                fmaxf(acc1[2 * j + 1], 0.0f));
            }
            // next-layer B-fragments: frag F dword d holds k = 16F+8g+2d..+1
#pragma unroll
            for (int F = 0; F < 4; ++F) {
                const int t = F >> 1;
                int dw[4];
#pragma unroll
                for (int p = 0; p < 2; ++p) {
                    int xv = c[t][((2 * F) & 3) * 2 + p];
                    int yv = c[t][((2 * F + 1) & 3) * 2 + p];
                    plswap(xv, yv);          // xv={x_lo,y_lo} yv={x_hi,y_hi}
                    dw[p]     = xv;
                    dw[p + 2] = yv;
                }
                int4 packed = make_int4(dw[0], dw[1], dw[2], dw[3]);
                h[F] = __builtin_bit_cast(f16x8, packed);
            }
        }

        // ---- final layer: SWAPPED operands, A=h, B=W (col = feature) -------
        {
            f32x16 acc0, acc1;
#pragma unroll
            for (int i = 0; i < 16; ++i) { acc0[i] = 0.0f; acc1[i] = 0.0f; }

            const f16x8* WL = &Wlds[(NLAYER - 1) * 8 * 64];
#pragma unroll
            for (int f = 0; f < 4; ++f) {
                acc0 = __builtin_amdgcn_mfma_f32_32x32x16_f16(
                           h[f], WL[f * 64 + lane],       acc0, 0, 0, 0);
                acc1 = __builtin_amdgcn_mfma_f32_32x32x16_f16(
                           h[f], WL[(4 + f) * 64 + lane], acc1, 0, 0, 0);
            }

            // lane holds feature bl (acc0) / bl+32 (acc1) of rows
            //   row_local(r,g) = (r&3) + 8*(r>>2) + 4g.
            // Each dword store = 2 full 128B chunks (fully coalesced).
            float* o0 = out + (size_t)(base + 4 * g) * 64 + bl;
#pragma unroll
            for (int r = 0; r < 16; ++r) {
                const int off = ((r & 3) + 8 * (r >> 2)) * 64;
                o0[off]      = acc0[r];
                o0[off + 32] = acc1[r];
            }
        }
    }
}

extern "C" void kernel_launch(void* const* d_in, const int* in_sizes, int n_in,
                              void* d_out, int out_size, void* d_ws, size_t ws_size,
                              hipStream_t stream)
{
    const float* x    = (const float*)d_in[0];
    const float* w_in = (const float*)d_in[1];
    const float* w_h  = (const float*)d_in[2];
    const float* w_o  = (const float*)d_in[3];

    _Float16* wf = (_Float16*)d_ws;                 // 20480 halves = 40 KB
    prep_weights<<<80, 256, 0, stream>>>(w_in, w_h, w_o, wf);
    mlp_kernel<<<GRID, BLOCK, 0, stream>>>(x, (const f16x8*)d_ws, (float*)d_out);
}